// Round 6
// baseline (3033.430 us; speedup 1.0000x reference)
//
#include <hip/hip_runtime.h>
#include <math.h>

#define BATCH 16
#define IN 128
#define HD 32
#define NN 2048
#define NE 32768
#define SEQ 100
#define BH (BATCH * HD)     // 512
#define WPITCH 34           // padded row pitch for transposed Wg (float2-aligned, conflict-free)
#define NPB 4               // nodes per block
#define NBLK (NN / NPB)     // 512 blocks; capacity 4/CU x 256 CU = 1024 -> 2x co-residency margin
#define GSZ 32              // blocks per barrier group
#define NGRP (NBLK / GSZ)   // 16 groups

// ---------------- preprocessing ----------------

__global__ void count_deg(const int* __restrict__ src, const int* __restrict__ dst,
                          int* deg_out, int* deg_in) {
    int e = blockIdx.x * blockDim.x + threadIdx.x;
    if (e < NE) {
        atomicAdd(&deg_out[src[e]], 1);
        atomicAdd(&deg_in[dst[e]], 1);
    }
}

__global__ void scan_rowptr(const int* __restrict__ deg_in, int* __restrict__ row_ptr) {
    __shared__ int partial[256];
    int t = threadIdx.x;
    int base = t * 8;
    int vals[8];
    int s = 0;
    for (int j = 0; j < 8; j++) { vals[j] = deg_in[base + j]; s += vals[j]; }
    partial[t] = s;
    __syncthreads();
    if (t == 0) {
        int acc = 0;
        for (int i = 0; i < 256; i++) { int v = partial[i]; partial[i] = acc; acc += v; }
        row_ptr[NN] = acc;
    }
    __syncthreads();
    int acc = partial[t];
    for (int j = 0; j < 8; j++) { row_ptr[base + j] = acc; acc += vals[j]; }
}

__global__ void scatter_edges(const int* __restrict__ src, const int* __restrict__ dst,
                              const int* __restrict__ deg_out, const int* __restrict__ deg_in,
                              const int* __restrict__ row_ptr, int* __restrict__ cursor,
                              int* __restrict__ col_idx, float* __restrict__ wgt) {
    int e = blockIdx.x * blockDim.x + threadIdx.x;
    if (e < NE) {
        int s = src[e], d = dst[e];
        int pos = row_ptr[d] + atomicAdd(&cursor[d], 1);
        col_idx[pos] = s;
        float doo = (float)max(deg_out[s], 1);
        float dii = (float)max(deg_in[d], 1);
        wgt[pos] = rsqrtf(doo * dii);
    }
}

__global__ void xgates(const float* __restrict__ x,
                       const float* __restrict__ Wr, const float* __restrict__ br,
                       const float* __restrict__ Wz, const float* __restrict__ bz,
                       const float* __restrict__ Wh, const float* __restrict__ bh,
                       float* __restrict__ xr, float* __restrict__ xz, float* __restrict__ xh) {
    int t = blockIdx.x * blockDim.x + threadIdx.x;
    if (t < BATCH * HD) {
        int b = t / HD, hh = t % HD;
        float ar = br[hh], az = bz[hh], ah = bh[hh];
        const float* xb = x + b * IN;
        for (int i = 0; i < IN; i++) {
            float xv = xb[i];
            ar += xv * Wr[i * HD + hh];
            az += xv * Wz[i * HD + hh];
            ah += xv * Wh[i * HD + hh];
        }
        xr[t] = ar; xz[t] = az; xh[t] = ah;
    }
}

// ---------------- custom grid barrier ----------------
// Two-level tree, monotonic counters (no reset -> no reset race), s_sleep backoff.
// lvl1: NGRP counters, each on its own 128B line. root: 1 counter.
// step s (1-based): lvl1 target = GSZ*s, root target = NGRP*s.

__device__ __forceinline__ void grid_sync_custom(unsigned* __restrict__ lvl1,
                                                 unsigned* __restrict__ root,
                                                 unsigned step) {
    __syncthreads();                       // all block work complete
    if (threadIdx.x == 0) {
        const int gid = blockIdx.x / GSZ;
        __builtin_amdgcn_fence(__ATOMIC_RELEASE, "agent");   // make hnext writes agent-visible
        __hip_atomic_fetch_add(&lvl1[gid * 32], 1u, __ATOMIC_RELAXED,
                               __HIP_MEMORY_SCOPE_AGENT);
        if ((blockIdx.x % GSZ) == 0) {
            while (__hip_atomic_load(&lvl1[gid * 32], __ATOMIC_RELAXED,
                                     __HIP_MEMORY_SCOPE_AGENT) < GSZ * step)
                __builtin_amdgcn_s_sleep(2);
            __hip_atomic_fetch_add(root, 1u, __ATOMIC_RELAXED,
                                   __HIP_MEMORY_SCOPE_AGENT);
        }
        while (__hip_atomic_load(root, __ATOMIC_RELAXED,
                                 __HIP_MEMORY_SCOPE_AGENT) < NGRP * step)
            __builtin_amdgcn_s_sleep(2);
        __builtin_amdgcn_fence(__ATOMIC_ACQUIRE, "agent");   // invalidate stale caches
    }
    __syncthreads();
}

// ---------------- step body ----------------
// h layout: [N][B][H]; thread tid -> (b = tid>>5, l = tid&31)

__device__ __forceinline__ float fast_sigmoid(float x) {
    return __builtin_amdgcn_rcpf(1.f + __expf(-x));
}

__device__ __forceinline__ void gru_step(
    int tid, int b, int l, int n0, int t,
    const float* __restrict__ hprev, float* __restrict__ hnext,
    const int* __restrict__ lstart_s, const int* __restrict__ gstart_s, bool use_lds,
    const int* __restrict__ ecol_s, const float* __restrict__ ewgt_s,
    const int* __restrict__ col_idx, const float* __restrict__ wgt,
    const float* __restrict__ wgT_s, float* __restrict__ aggL,
    float xrv, float xzv, float xhv, float bgv,
    float* __restrict__ out)
{
#pragma unroll
    for (int nd = 0; nd < NPB; nd++) {
        float agg = 0.f;
        if (use_lds) {
            const int s = lstart_s[nd], epd = lstart_s[nd + 1];
            int e = s;
            for (; e + 4 <= epd; e += 4) {
                int c0 = ecol_s[e], c1 = ecol_s[e + 1], c2 = ecol_s[e + 2], c3 = ecol_s[e + 3];
                float w0 = ewgt_s[e], w1 = ewgt_s[e + 1], w2 = ewgt_s[e + 2], w3 = ewgt_s[e + 3];
                float v0 = hprev[c0 + tid];
                float v1 = hprev[c1 + tid];
                float v2 = hprev[c2 + tid];
                float v3 = hprev[c3 + tid];
                agg = fmaf(w0, v0, agg); agg = fmaf(w1, v1, agg);
                agg = fmaf(w2, v2, agg); agg = fmaf(w3, v3, agg);
            }
            for (; e < epd; e++)
                agg = fmaf(ewgt_s[e], hprev[ecol_s[e] + tid], agg);
        } else {
            const int s = gstart_s[nd], epd = gstart_s[nd + 1];
            for (int e = s; e < epd; e++)
                agg = fmaf(wgt[e], hprev[col_idx[e] * BH + tid], agg);
        }

        // matvec: conv[l] = bg[l] + sum_k agg[k] * Wg[k][l]
        // agg broadcast via LDS; writer wave == reader wave -> lockstep, no barrier
        aggL[tid] = agg;
        const float4* arow = (const float4*)&aggL[tid & ~31];
        const float2* wrow = (const float2*)&wgT_s[l * WPITCH];
        float conv = bgv;
#pragma unroll
        for (int kq = 0; kq < 8; kq++) {
            float4 a4 = arow[kq];
            float2 u0 = wrow[2 * kq], u1 = wrow[2 * kq + 1];
            conv = fmaf(a4.x, u0.x, conv);
            conv = fmaf(a4.y, u0.y, conv);
            conv = fmaf(a4.z, u1.x, conv);
            conv = fmaf(a4.w, u1.y, conv);
        }

        const float r = fast_sigmoid(xrv + conv);
        const float z = fast_sigmoid(xzv + conv);
        const float e2 = __expf(2.f * (xhv + r * conv));
        const float ht = 1.f - 2.f * __builtin_amdgcn_rcpf(e2 + 1.f);
        const int n = n0 + nd;
        const float hp = hprev[n * BH + tid];
        const float hn = (1.f - z) * hp + z * ht;

        hnext[n * BH + tid] = hn;
        __builtin_nontemporal_store(
            hn, &out[((size_t)b * SEQ + t) * (NN * HD) + (size_t)n * HD + l]);
    }
}

// ---------------- persistent kernel (REGULAR launch + custom barrier) ----------------

__global__ void __launch_bounds__(512) gru_persistent(
    float* __restrict__ hA, float* __restrict__ hB,
    const int* __restrict__ row_ptr, const int* __restrict__ col_idx,
    const float* __restrict__ wgt,
    const float* __restrict__ Wg, const float* __restrict__ bg,
    const float* __restrict__ xr, const float* __restrict__ xz,
    const float* __restrict__ xh,
    float* __restrict__ out,
    unsigned* __restrict__ bar_lvl1, unsigned* __restrict__ bar_root)
{
    constexpr int ECAP = 128 * NPB;
    __shared__ float wgT_s[HD * WPITCH];
    __shared__ float aggL[512];
    __shared__ int   ecol_s[ECAP];
    __shared__ float ewgt_s[ECAP];
    __shared__ int   gstart_s[NPB + 1];
    __shared__ int   lstart_s[NPB + 1];

    const int tid = threadIdx.x;
    const int b = tid >> 5;
    const int l = tid & 31;
    const int n0 = blockIdx.x * NPB;

    for (int i = tid; i < HD * HD; i += 512) {
        int k = i >> 5, c = i & 31;
        wgT_s[c * WPITCH + k] = Wg[i];
    }
    if (tid <= NPB) gstart_s[tid] = row_ptr[n0 + tid];
    __syncthreads();

    const int e0 = gstart_s[0];
    const int ecount = gstart_s[NPB] - e0;
    if (tid <= NPB) lstart_s[tid] = gstart_s[tid] - e0;
    const bool use_lds = (ecount <= ECAP);
    if (use_lds) {
        for (int i = tid; i < ecount; i += 512) {
            ecol_s[i] = col_idx[e0 + i] * BH;
            ewgt_s[i] = wgt[e0 + i];
        }
    }
    __syncthreads();

    const float xrv = xr[b * HD + l];
    const float xzv = xz[b * HD + l];
    const float xhv = xh[b * HD + l];
    const float bgv = bg[l];

    const float* hprev = hA;
    float*       hnext = hB;

    for (int t = 0; t < SEQ; t++) {
        gru_step(tid, b, l, n0, t, hprev, hnext, lstart_s, gstart_s, use_lds,
                 ecol_s, ewgt_s, col_idx, wgt, wgT_s, aggL,
                 xrv, xzv, xhv, bgv, out);
        if (t != SEQ - 1)
            grid_sync_custom(bar_lvl1, bar_root, (unsigned)(t + 1));
        float* tmp = (float*)hprev; hprev = hnext; hnext = tmp;
    }
}

// ---------------- launch ----------------

extern "C" void kernel_launch(void* const* d_in, const int* in_sizes, int n_in,
                              void* d_out, int out_size, void* d_ws, size_t ws_size,
                              hipStream_t stream) {
    const float* x   = (const float*)d_in[0];
    const int*   src = (const int*)d_in[1];
    const int*   dst = (const int*)d_in[2];
    const float* Wr  = (const float*)d_in[3];
    const float* br  = (const float*)d_in[4];
    const float* Wz  = (const float*)d_in[5];
    const float* bz  = (const float*)d_in[6];
    const float* Wh  = (const float*)d_in[7];
    const float* bh  = (const float*)d_in[8];
    const float* Wg  = (const float*)d_in[9];
    const float* bg  = (const float*)d_in[10];
    float* out = (float*)d_out;

    char* ws = (char*)d_ws;
    float* h0 = (float*)ws;            ws += (size_t)BATCH * NN * HD * 4;
    float* h1 = (float*)ws;            ws += (size_t)BATCH * NN * HD * 4;
    float* xr = (float*)ws;            ws += BATCH * HD * 4;
    float* xz = (float*)ws;            ws += BATCH * HD * 4;
    float* xh = (float*)ws;            ws += BATCH * HD * 4;
    int* deg_out = (int*)ws;           ws += NN * 4;
    int* deg_in  = (int*)ws;           ws += NN * 4;
    int* cursor  = (int*)ws;           ws += NN * 4;
    int* row_ptr = (int*)ws;           ws += (NN + 1) * 4;
    int* col_idx = (int*)ws;           ws += NE * 4;
    float* wgt   = (float*)ws;         ws += NE * 4;
    // barrier counters: NGRP group counters (128B apart) + 1 root line; zeroed per call
    unsigned* bar_lvl1 = (unsigned*)ws; ws += NGRP * 32 * 4;
    unsigned* bar_root = (unsigned*)ws; ws += 32 * 4;

    hipMemsetAsync(h0, 0, (size_t)BATCH * NN * HD * 4, stream);
    hipMemsetAsync(deg_out, 0, 3 * NN * 4, stream);
    hipMemsetAsync(bar_lvl1, 0, (NGRP * 32 + 32) * 4, stream);

    count_deg<<<NE / 256, 256, 0, stream>>>(src, dst, deg_out, deg_in);
    scan_rowptr<<<1, 256, 0, stream>>>(deg_in, row_ptr);
    scatter_edges<<<NE / 256, 256, 0, stream>>>(src, dst, deg_out, deg_in, row_ptr,
                                                cursor, col_idx, wgt);
    xgates<<<2, 256, 0, stream>>>(x, Wr, br, Wz, bz, Wh, bh, xr, xz, xh);

    // Regular launch (graph-capture-safe). Co-residency by construction:
    // 512 blocks, 4 blocks/CU capacity x 256 CU = 1024 slots (2x margin).
    gru_persistent<<<dim3(NBLK), dim3(512), 0, stream>>>(
        h0, h1, row_ptr, col_idx, wgt, Wg, bg, xr, xz, xh, out,
        bar_lvl1, bar_root);
}

// Round 7
// 1177.106 us; speedup vs baseline: 2.5770x; 2.5770x over previous
//
#include <hip/hip_runtime.h>
#include <math.h>

#define BATCH 16
#define IN 128
#define HD 32
#define NN 2048
#define NE 32768
#define SEQ 100
#define TPB 512
#define NBLK 512            // 2 blocks/CU (capacity 4/CU -> 2x co-residency margin)
#define GSZ 32              // global barrier: blocks per group
#define NGRP (NBLK / GSZ)   // 16
#define NXCD 8

// ---------------- preprocessing ----------------

__global__ void count_deg(const int* __restrict__ src, const int* __restrict__ dst,
                          int* deg_out, int* deg_in) {
    int e = blockIdx.x * blockDim.x + threadIdx.x;
    if (e < NE) {
        atomicAdd(&deg_out[src[e]], 1);
        atomicAdd(&deg_in[dst[e]], 1);
    }
}

__global__ void scan_rowptr(const int* __restrict__ deg_in, int* __restrict__ row_ptr) {
    __shared__ int partial[256];
    int t = threadIdx.x;
    int base = t * 8;
    int vals[8];
    int s = 0;
    for (int j = 0; j < 8; j++) { vals[j] = deg_in[base + j]; s += vals[j]; }
    partial[t] = s;
    __syncthreads();
    if (t == 0) {
        int acc = 0;
        for (int i = 0; i < 256; i++) { int v = partial[i]; partial[i] = acc; acc += v; }
        row_ptr[NN] = acc;
    }
    __syncthreads();
    int acc = partial[t];
    for (int j = 0; j < 8; j++) { row_ptr[base + j] = acc; acc += vals[j]; }
}

// col_idx stores src*HD (pre-scaled for the gather address math)
__global__ void scatter_edges(const int* __restrict__ src, const int* __restrict__ dst,
                              const int* __restrict__ deg_out, const int* __restrict__ deg_in,
                              const int* __restrict__ row_ptr, int* __restrict__ cursor,
                              int* __restrict__ col_idx, float* __restrict__ wgt) {
    int e = blockIdx.x * blockDim.x + threadIdx.x;
    if (e < NE) {
        int s = src[e], d = dst[e];
        int pos = row_ptr[d] + atomicAdd(&cursor[d], 1);
        col_idx[pos] = s * HD;
        float doo = (float)max(deg_out[s], 1);
        float dii = (float)max(deg_in[d], 1);
        wgt[pos] = rsqrtf(doo * dii);
    }
}

__global__ void xgates(const float* __restrict__ x,
                       const float* __restrict__ Wr, const float* __restrict__ br,
                       const float* __restrict__ Wz, const float* __restrict__ bz,
                       const float* __restrict__ Wh, const float* __restrict__ bh,
                       float* __restrict__ xr, float* __restrict__ xz, float* __restrict__ xh) {
    int t = blockIdx.x * blockDim.x + threadIdx.x;
    if (t < BATCH * HD) {
        int b = t / HD, hh = t % HD;
        float ar = br[hh], az = bz[hh], ah = bh[hh];
        const float* xb = x + b * IN;
        for (int i = 0; i < IN; i++) {
            float xv = xb[i];
            ar += xv * Wr[i * HD + hh];
            az += xv * Wz[i * HD + hh];
            ah += xv * Wh[i * HD + hh];
        }
        xr[t] = ar; xz[t] = az; xh[t] = ah;
    }
}

// ---------------- barriers ----------------

// Global two-level barrier with agent fences (proven in round 6).
__device__ __forceinline__ void global_barrier(unsigned* __restrict__ lvl1,
                                               unsigned* __restrict__ root,
                                               unsigned step) {
    __syncthreads();
    if (threadIdx.x == 0) {
        const int gid = blockIdx.x / GSZ;
        __builtin_amdgcn_fence(__ATOMIC_RELEASE, "agent");
        __hip_atomic_fetch_add(&lvl1[gid * 32], 1u, __ATOMIC_RELAXED,
                               __HIP_MEMORY_SCOPE_AGENT);
        if ((blockIdx.x % GSZ) == 0) {
            while (__hip_atomic_load(&lvl1[gid * 32], __ATOMIC_RELAXED,
                                     __HIP_MEMORY_SCOPE_AGENT) < GSZ * step)
                __builtin_amdgcn_s_sleep(2);
            __hip_atomic_fetch_add(root, 1u, __ATOMIC_RELAXED,
                                   __HIP_MEMORY_SCOPE_AGENT);
        }
        while (__hip_atomic_load(root, __ATOMIC_RELAXED,
                                 __HIP_MEMORY_SCOPE_AGENT) < NGRP * step)
            __builtin_amdgcn_s_sleep(2);
        __builtin_amdgcn_fence(__ATOMIC_ACQUIRE, "agent");
    }
    __syncthreads();
}

// Per-XCD barrier: all participants share one L2 -> no L2 flush/inv needed.
// __syncthreads drains vmcnt (release to L2, vL1 is write-through);
// buffer_inv sc0 invalidates the per-CU vL1 so re-reads hit fresh L2 lines.
__device__ __forceinline__ void xcd_barrier(unsigned* __restrict__ xcnt,
                                            unsigned* __restrict__ xgo,
                                            int xid, int slot, int cnt, unsigned s) {
    __syncthreads();
    if (threadIdx.x == 0) {
        __hip_atomic_fetch_add(&xcnt[xid * 32], 1u, __ATOMIC_RELAXED,
                               __HIP_MEMORY_SCOPE_AGENT);
        if (slot == 0) {
            while (__hip_atomic_load(&xcnt[xid * 32], __ATOMIC_RELAXED,
                                     __HIP_MEMORY_SCOPE_AGENT) < (unsigned)cnt * s)
                __builtin_amdgcn_s_sleep(1);
            __hip_atomic_store(&xgo[xid * 32], s, __ATOMIC_RELAXED,
                               __HIP_MEMORY_SCOPE_AGENT);
        } else {
            while (__hip_atomic_load(&xgo[xid * 32], __ATOMIC_RELAXED,
                                     __HIP_MEMORY_SCOPE_AGENT) < s)
                __builtin_amdgcn_s_sleep(1);
        }
    }
    __syncthreads();
    asm volatile("buffer_inv sc0\n\ts_waitcnt vmcnt(0)" ::: "memory");
}

// ---------------- persistent kernel ----------------
// h layout: [B][N][H]. Wave (64 lanes) = one node n for a batch PAIR:
// lanes 0-31 -> batch b0 (channels 0-31), lanes 32-63 -> batch b0+1.

__device__ __forceinline__ float fast_sigmoid(float x) {
    return __builtin_amdgcn_rcpf(1.f + __expf(-x));
}

__global__ void __launch_bounds__(TPB) gru_persistent(
    float* __restrict__ hA, float* __restrict__ hB,
    const int* __restrict__ row_ptr, const int* __restrict__ col_idx,
    const float* __restrict__ wgt,
    const float* __restrict__ Wg, const float* __restrict__ bg,
    const float* __restrict__ xr, const float* __restrict__ xz,
    const float* __restrict__ xh,
    float* __restrict__ out,
    unsigned* __restrict__ glvl1, unsigned* __restrict__ groot,
    unsigned* __restrict__ xreg, unsigned* __restrict__ xcnt,
    unsigned* __restrict__ xgo)
{
    __shared__ float aggL[TPB];
    __shared__ int shr_slot, shr_cnt, shr_mode;

    const int tid = threadIdx.x;
    const int lane = tid & 63;
    const int wid = tid >> 6;        // wave id in block (0..7)
    const int half = lane >> 5;      // 0 or 1 -> which batch of the pair
    const int l = lane & 31;         // channel

    // physical XCD id [measured on this chip: learn_hip m09]
    int xraw;
    asm volatile("s_getreg_b32 %0, hwreg(HW_REG_XCC_ID)" : "=s"(xraw));
    int xid = xraw & 7;

    if (tid == 0)
        shr_slot = (int)__hip_atomic_fetch_add(&xreg[xid * 32], 1u, __ATOMIC_RELAXED,
                                               __HIP_MEMORY_SCOPE_AGENT);
    __syncthreads();
    int slot = shr_slot;

    // settle registration across the grid
    global_barrier(glvl1, groot, 1u);

    if (tid == 0) {
        int sum = 0, mode = 1, mycnt = 0;
        for (int xx = 0; xx < NXCD; xx++) {
            int c = (int)__hip_atomic_load(&xreg[xx * 32], __ATOMIC_RELAXED,
                                           __HIP_MEMORY_SCOPE_AGENT);
            sum += c;
            if (c == 0) mode = 0;
            if (xx == xid) mycnt = c;
        }
        if (sum != NBLK) mode = 0;
        shr_mode = mode;
        shr_cnt = mycnt;
    }
    __syncthreads();
    const int xmode = shr_mode;
    int cnt;
    if (xmode) {
        cnt = shr_cnt;
    } else {            // fallback: virtual partition + global fenced barrier
        xid = blockIdx.x & 7;
        slot = blockIdx.x >> 3;
        cnt = NBLK / NXCD;
    }

    const int b0 = 2 * xid;
    const int bb = b0 + half;
    const float xrv = xr[bb * HD + l];
    const float xzv = xz[bb * HD + l];
    const float xhv = xh[bb * HD + l];
    const float bgv = bg[l];
    float wgreg[HD];
#pragma unroll
    for (int k = 0; k < HD; k++) wgreg[k] = Wg[k * HD + l];

    const size_t hbase = (size_t)bb * (NN * HD);
    const int wglob = slot * 8 + wid;   // wave index within this XCD's domain
    const int wtot = cnt * 8;

    const float* hprev = hA;
    float* hnext = hB;

    for (int t = 0; t < SEQ; t++) {
        for (int n = wglob; n < NN; n += wtot) {
            const int rs = row_ptr[n], re = row_ptr[n + 1];
            float agg = 0.f;
            int e = rs;
            for (; e + 4 <= re; e += 4) {
                int c0 = col_idx[e], c1 = col_idx[e + 1];
                int c2 = col_idx[e + 2], c3 = col_idx[e + 3];
                float w0 = wgt[e], w1 = wgt[e + 1], w2 = wgt[e + 2], w3 = wgt[e + 3];
                float v0 = hprev[hbase + c0 + l];
                float v1 = hprev[hbase + c1 + l];
                float v2 = hprev[hbase + c2 + l];
                float v3 = hprev[hbase + c3 + l];
                agg = fmaf(w0, v0, agg); agg = fmaf(w1, v1, agg);
                agg = fmaf(w2, v2, agg); agg = fmaf(w3, v3, agg);
            }
            for (; e < re; e++)
                agg = fmaf(wgt[e], hprev[hbase + col_idx[e] + l], agg);

            // matvec: conv[l] = bg[l] + sum_k agg[k] * Wg[k][l]
            // per-wave LDS broadcast (writer wave == reader wave -> lockstep)
            aggL[tid] = agg;
            const float4* arow = (const float4*)&aggL[(tid & ~63) + (half << 5)];
            float conv = bgv;
#pragma unroll
            for (int kq = 0; kq < 8; kq++) {
                float4 a4 = arow[kq];
                conv = fmaf(a4.x, wgreg[4 * kq + 0], conv);
                conv = fmaf(a4.y, wgreg[4 * kq + 1], conv);
                conv = fmaf(a4.z, wgreg[4 * kq + 2], conv);
                conv = fmaf(a4.w, wgreg[4 * kq + 3], conv);
            }

            const float r = fast_sigmoid(xrv + conv);
            const float z = fast_sigmoid(xzv + conv);
            const float e2 = __expf(2.f * (xhv + r * conv));
            const float ht = 1.f - 2.f * __builtin_amdgcn_rcpf(e2 + 1.f);
            const float hp = hprev[hbase + n * HD + l];
            const float hn = (1.f - z) * hp + z * ht;

            hnext[hbase + n * HD + l] = hn;
            __builtin_nontemporal_store(
                hn, &out[((size_t)bb * SEQ + t) * (NN * HD) + n * HD + l]);
        }
        if (t != SEQ - 1) {
            if (xmode)
                xcd_barrier(xcnt, xgo, xid, slot, cnt, (unsigned)(t + 1));
            else
                global_barrier(glvl1, groot, (unsigned)(t + 2));
        }
        const float* tmp = hprev; hprev = hnext; hnext = (float*)tmp;
    }
}

// ---------------- launch ----------------

extern "C" void kernel_launch(void* const* d_in, const int* in_sizes, int n_in,
                              void* d_out, int out_size, void* d_ws, size_t ws_size,
                              hipStream_t stream) {
    const float* x   = (const float*)d_in[0];
    const int*   src = (const int*)d_in[1];
    const int*   dst = (const int*)d_in[2];
    const float* Wr  = (const float*)d_in[3];
    const float* br  = (const float*)d_in[4];
    const float* Wz  = (const float*)d_in[5];
    const float* bz  = (const float*)d_in[6];
    const float* Wh  = (const float*)d_in[7];
    const float* bh  = (const float*)d_in[8];
    const float* Wg  = (const float*)d_in[9];
    const float* bg  = (const float*)d_in[10];
    float* out = (float*)d_out;

    char* ws = (char*)d_ws;
    float* h0 = (float*)ws;            ws += (size_t)BATCH * NN * HD * 4;
    float* h1 = (float*)ws;            ws += (size_t)BATCH * NN * HD * 4;
    float* xr = (float*)ws;            ws += BATCH * HD * 4;
    float* xz = (float*)ws;            ws += BATCH * HD * 4;
    float* xh = (float*)ws;            ws += BATCH * HD * 4;
    int* deg_out = (int*)ws;           ws += NN * 4;
    int* deg_in  = (int*)ws;           ws += NN * 4;
    int* cursor  = (int*)ws;           ws += NN * 4;
    int* row_ptr = (int*)ws;           ws += (NN + 1) * 4;
    int* col_idx = (int*)ws;           ws += NE * 4;
    float* wgt   = (float*)ws;         ws += NE * 4;
    // barrier/registration counters (contiguous; zeroed per call)
    unsigned* glvl1 = (unsigned*)ws;   ws += NGRP * 32 * 4;
    unsigned* groot = (unsigned*)ws;   ws += 32 * 4;
    unsigned* xreg  = (unsigned*)ws;   ws += NXCD * 32 * 4;
    unsigned* xcnt  = (unsigned*)ws;   ws += NXCD * 32 * 4;
    unsigned* xgo   = (unsigned*)ws;   ws += NXCD * 32 * 4;

    hipMemsetAsync(h0, 0, (size_t)BATCH * NN * HD * 4, stream);
    hipMemsetAsync(deg_out, 0, 3 * NN * 4, stream);
    hipMemsetAsync(glvl1, 0, (NGRP * 32 + 32 + 3 * NXCD * 32) * 4, stream);

    count_deg<<<NE / 256, 256, 0, stream>>>(src, dst, deg_out, deg_in);
    scan_rowptr<<<1, 256, 0, stream>>>(deg_in, row_ptr);
    scatter_edges<<<NE / 256, 256, 0, stream>>>(src, dst, deg_out, deg_in, row_ptr,
                                                cursor, col_idx, wgt);
    xgates<<<2, 256, 0, stream>>>(x, Wr, br, Wz, bz, Wh, bh, xr, xz, xh);

    gru_persistent<<<dim3(NBLK), dim3(TPB), 0, stream>>>(
        h0, h1, row_ptr, col_idx, wgt, Wg, bg, xr, xz, xh, out,
        glvl1, groot, xreg, xcnt, xgo);
}

// Round 8
// 790.141 us; speedup vs baseline: 3.8391x; 1.4897x over previous
//
#include <hip/hip_runtime.h>
#include <math.h>

#define BATCH 16
#define IN 128
#define HD 32
#define NN 2048
#define NE 32768
#define SEQ 100
#define TPB 512
#define NBLK 512            // 2 blocks/CU (capacity >=4/CU -> 2x co-residency margin)
#define GSZ 32              // global barrier: blocks per group
#define NGRP (NBLK / GSZ)   // 16
#define NXCD 8
#define MAXJ 64             // max (k,wave) node slots per block
#define ECAP 1536           // LDS edge cache entries (int2, 12 KB); avg ~512+pad

// ---------------- preprocessing ----------------

__global__ void count_deg(const int* __restrict__ src, const int* __restrict__ dst,
                          int* deg_out, int* deg_in) {
    int e = blockIdx.x * blockDim.x + threadIdx.x;
    if (e < NE) {
        atomicAdd(&deg_out[src[e]], 1);
        atomicAdd(&deg_in[dst[e]], 1);
    }
}

__global__ void scan_rowptr(const int* __restrict__ deg_in, int* __restrict__ row_ptr) {
    __shared__ int partial[256];
    int t = threadIdx.x;
    int base = t * 8;
    int vals[8];
    int s = 0;
    for (int j = 0; j < 8; j++) { vals[j] = deg_in[base + j]; s += vals[j]; }
    partial[t] = s;
    __syncthreads();
    if (t == 0) {
        int acc = 0;
        for (int i = 0; i < 256; i++) { int v = partial[i]; partial[i] = acc; acc += v; }
        row_ptr[NN] = acc;
    }
    __syncthreads();
    int acc = partial[t];
    for (int j = 0; j < 8; j++) { row_ptr[base + j] = acc; acc += vals[j]; }
}

// col_idx stores src*HD (element offset of the source node's row)
__global__ void scatter_edges(const int* __restrict__ src, const int* __restrict__ dst,
                              const int* __restrict__ deg_out, const int* __restrict__ deg_in,
                              const int* __restrict__ row_ptr, int* __restrict__ cursor,
                              int* __restrict__ col_idx, float* __restrict__ wgt) {
    int e = blockIdx.x * blockDim.x + threadIdx.x;
    if (e < NE) {
        int s = src[e], d = dst[e];
        int pos = row_ptr[d] + atomicAdd(&cursor[d], 1);
        col_idx[pos] = s * HD;
        float doo = (float)max(deg_out[s], 1);
        float dii = (float)max(deg_in[d], 1);
        wgt[pos] = rsqrtf(doo * dii);
    }
}

__global__ void xgates(const float* __restrict__ x,
                       const float* __restrict__ Wr, const float* __restrict__ br,
                       const float* __restrict__ Wz, const float* __restrict__ bz,
                       const float* __restrict__ Wh, const float* __restrict__ bh,
                       float* __restrict__ xr, float* __restrict__ xz, float* __restrict__ xh) {
    int t = blockIdx.x * blockDim.x + threadIdx.x;
    if (t < BATCH * HD) {
        int b = t / HD, hh = t % HD;
        float ar = br[hh], az = bz[hh], ah = bh[hh];
        const float* xb = x + b * IN;
        for (int i = 0; i < IN; i++) {
            float xv = xb[i];
            ar += xv * Wr[i * HD + hh];
            az += xv * Wz[i * HD + hh];
            ah += xv * Wh[i * HD + hh];
        }
        xr[t] = ar; xz[t] = az; xh[t] = ah;
    }
}

// ---------------- barriers ----------------

// Global two-level barrier with agent fences (proven round 6).
__device__ __forceinline__ void global_barrier(unsigned* __restrict__ lvl1,
                                               unsigned* __restrict__ root,
                                               unsigned step) {
    __syncthreads();
    if (threadIdx.x == 0) {
        const int gid = blockIdx.x / GSZ;
        __builtin_amdgcn_fence(__ATOMIC_RELEASE, "agent");
        __hip_atomic_fetch_add(&lvl1[gid * 32], 1u, __ATOMIC_RELAXED,
                               __HIP_MEMORY_SCOPE_AGENT);
        if ((blockIdx.x % GSZ) == 0) {
            while (__hip_atomic_load(&lvl1[gid * 32], __ATOMIC_RELAXED,
                                     __HIP_MEMORY_SCOPE_AGENT) < GSZ * step)
                __builtin_amdgcn_s_sleep(2);
            __hip_atomic_fetch_add(root, 1u, __ATOMIC_RELAXED,
                                   __HIP_MEMORY_SCOPE_AGENT);
        }
        while (__hip_atomic_load(root, __ATOMIC_RELAXED,
                                 __HIP_MEMORY_SCOPE_AGENT) < NGRP * step)
            __builtin_amdgcn_s_sleep(2);
        __builtin_amdgcn_fence(__ATOMIC_ACQUIRE, "agent");
    }
    __syncthreads();
}

// Per-XCD barrier (proven round 7): producers/consumers share one L2.
__device__ __forceinline__ void xcd_barrier(unsigned* __restrict__ xcnt,
                                            unsigned* __restrict__ xgo,
                                            int xid, int slot, int cnt, unsigned s) {
    __syncthreads();
    if (threadIdx.x == 0) {
        __hip_atomic_fetch_add(&xcnt[xid * 32], 1u, __ATOMIC_RELAXED,
                               __HIP_MEMORY_SCOPE_AGENT);
        if (slot == 0) {
            while (__hip_atomic_load(&xcnt[xid * 32], __ATOMIC_RELAXED,
                                     __HIP_MEMORY_SCOPE_AGENT) < (unsigned)cnt * s)
                __builtin_amdgcn_s_sleep(1);
            __hip_atomic_store(&xgo[xid * 32], s, __ATOMIC_RELAXED,
                               __HIP_MEMORY_SCOPE_AGENT);
        } else {
            while (__hip_atomic_load(&xgo[xid * 32], __ATOMIC_RELAXED,
                                     __HIP_MEMORY_SCOPE_AGENT) < s)
                __builtin_amdgcn_s_sleep(1);
        }
    }
    __syncthreads();
    asm volatile("buffer_inv sc0\n\ts_waitcnt vmcnt(0)" ::: "memory");
}

// ---------------- persistent kernel ----------------
// h layout: [B][N][H]. Wave = one node for a batch PAIR:
// lanes 0-31 -> batch b0 (ch 0-31), lanes 32-63 -> batch b0+1.

__device__ __forceinline__ float fast_sigmoid(float x) {
    return __builtin_amdgcn_rcpf(1.f + __expf(-x));
}

__global__ void __launch_bounds__(TPB) gru_persistent(
    float* __restrict__ hA, float* __restrict__ hB,
    const int* __restrict__ row_ptr, const int* __restrict__ col_idx,
    const float* __restrict__ wgt,
    const float* __restrict__ Wg, const float* __restrict__ bg,
    const float* __restrict__ xr, const float* __restrict__ xz,
    const float* __restrict__ xh,
    float* __restrict__ out,
    unsigned* __restrict__ glvl1, unsigned* __restrict__ groot,
    unsigned* __restrict__ xreg, unsigned* __restrict__ xcnt,
    unsigned* __restrict__ xgo)
{
    __shared__ float aggL[TPB];
    __shared__ int jn[MAXJ], jrs[MAXJ], jraw[MAXJ], jplen[MAXJ], jofs[MAXJ];
    __shared__ __align__(16) int2 eLDS[ECAP];   // (byte-offset, bitcast weight)
    __shared__ int shr_slot, shr_cnt, shr_mode, shr_use;

    const int tid = threadIdx.x;
    const int lane = tid & 63;
    const int wid = tid >> 6;        // wave id (0..7)
    const int half = lane >> 5;      // which batch of the pair
    const int l = lane & 31;         // channel

    // physical XCD id [measured: learn_hip m09]
    int xraw;
    asm volatile("s_getreg_b32 %0, hwreg(HW_REG_XCC_ID)" : "=s"(xraw));
    int xid = xraw & 7;

    if (tid == 0)
        shr_slot = (int)__hip_atomic_fetch_add(&xreg[xid * 32], 1u, __ATOMIC_RELAXED,
                                               __HIP_MEMORY_SCOPE_AGENT);
    __syncthreads();
    int slot = shr_slot;

    global_barrier(glvl1, groot, 1u);   // settle registration

    if (tid == 0) {
        int sum = 0, mode = 1, mycnt = 0;
        for (int xx = 0; xx < NXCD; xx++) {
            int c = (int)__hip_atomic_load(&xreg[xx * 32], __ATOMIC_RELAXED,
                                           __HIP_MEMORY_SCOPE_AGENT);
            sum += c;
            if (c < 32) mode = 0;       // also guarantees kmax <= 8
            if (xx == xid) mycnt = c;
        }
        if (sum != NBLK) mode = 0;
        shr_mode = mode;
        shr_cnt = mycnt;
    }
    __syncthreads();
    const int xmode = shr_mode;
    int cnt = shr_cnt;
    if (!xmode) { xid = blockIdx.x & 7; slot = blockIdx.x >> 3; cnt = NBLK / NXCD; }
    const int wtot = cnt * 8;

    // ---- per-block node metadata (j = k*8 + waveid) ----
    if (tid < MAXJ) {
        int k = tid >> 3, w = tid & 7;
        int n = slot * 8 + w + k * wtot;
        if (n < NN) {
            int rs = row_ptr[n], re = row_ptr[n + 1];
            jn[tid] = n; jrs[tid] = rs; jraw[tid] = re - rs;
            jplen[tid] = (re - rs + 7) & ~7;
        } else {
            jn[tid] = -1; jrs[tid] = 0; jraw[tid] = 0; jplen[tid] = 0;
        }
    }
    __syncthreads();
    if (tid == 0) {
        int o = 0;
        for (int j = 0; j < MAXJ; j++) { jofs[j] = o; o += jplen[j]; }
        shr_use = (o <= ECAP);
    }
    __syncthreads();
    const bool use_lds = (shr_use != 0);

    // ---- stage edges into LDS once (time-invariant), padded to x8 ----
    if (use_lds) {
        for (int k = 0; k < 8; k++) {
            int j = k * 8 + wid;
            if (jn[j] < 0) break;
            int rs = jrs[j], raw = jraw[j], pl = jplen[j], of = jofs[j];
            for (int i = lane; i < pl; i += 64) {
                int2 v;
                if (i < raw) { v.x = col_idx[rs + i] << 2; v.y = __float_as_int(wgt[rs + i]); }
                else         { v.x = 0; v.y = 0; }
                eLDS[of + i] = v;
            }
        }
    }
    __syncthreads();

    // ---- per-thread constants ----
    const int bb = 2 * xid + half;
    const float xrv = xr[bb * HD + l];
    const float xzv = xz[bb * HD + l];
    const float xhv = xh[bb * HD + l];
    const float bgv = bg[l];
    float wgreg[HD];
#pragma unroll
    for (int k = 0; k < HD; k++) wgreg[k] = Wg[k * HD + l];

    const int hoffb = (bb * (NN * HD) + l) * 4;         // byte offset of this thread's lane
    float* outp = out + (size_t)bb * SEQ * (NN * HD) + l;

    const char* hprev = (const char*)hA;
    char* hnext = (char*)hB;

    for (int t = 0; t < SEQ; t++) {
        for (int k = 0; k < 8; k++) {
            const int j = k * 8 + wid;
            const int n = jn[j];
            if (n < 0) break;

            float agg = 0.f;
            if (use_lds) {
                const int4* ep = (const int4*)&eLDS[jofs[j]];   // 2 edges per int4
                const int pl = jplen[j];
                for (int e = 0; e < pl; e += 8) {
                    int4 p0 = ep[0], p1 = ep[1], p2 = ep[2], p3 = ep[3];
                    ep += 4;
                    float v0 = *(const float*)(hprev + (hoffb + p0.x));
                    float v1 = *(const float*)(hprev + (hoffb + p0.z));
                    float v2 = *(const float*)(hprev + (hoffb + p1.x));
                    float v3 = *(const float*)(hprev + (hoffb + p1.z));
                    float v4 = *(const float*)(hprev + (hoffb + p2.x));
                    float v5 = *(const float*)(hprev + (hoffb + p2.z));
                    float v6 = *(const float*)(hprev + (hoffb + p3.x));
                    float v7 = *(const float*)(hprev + (hoffb + p3.z));
                    agg = fmaf(__int_as_float(p0.y), v0, agg);
                    agg = fmaf(__int_as_float(p0.w), v1, agg);
                    agg = fmaf(__int_as_float(p1.y), v2, agg);
                    agg = fmaf(__int_as_float(p1.w), v3, agg);
                    agg = fmaf(__int_as_float(p2.y), v4, agg);
                    agg = fmaf(__int_as_float(p2.w), v5, agg);
                    agg = fmaf(__int_as_float(p3.y), v6, agg);
                    agg = fmaf(__int_as_float(p3.w), v7, agg);
                }
            } else {   // rare overflow path: stream from global
                const int rs = jrs[j], re = rs + jraw[j];
                for (int e = rs; e < re; e++) {
                    int cb = col_idx[e] << 2;
                    agg = fmaf(wgt[e], *(const float*)(hprev + (hoffb + cb)), agg);
                }
            }

            // matvec: conv[l] = bg[l] + sum_k agg[k] * Wg[k][l]
            // per-wave LDS broadcast (writer wave == reader wave -> lockstep)
            aggL[tid] = agg;
            const float4* arow = (const float4*)&aggL[(tid & ~63) + (half << 5)];
            float conv = bgv;
#pragma unroll
            for (int kq = 0; kq < 8; kq++) {
                float4 a4 = arow[kq];
                conv = fmaf(a4.x, wgreg[4 * kq + 0], conv);
                conv = fmaf(a4.y, wgreg[4 * kq + 1], conv);
                conv = fmaf(a4.z, wgreg[4 * kq + 2], conv);
                conv = fmaf(a4.w, wgreg[4 * kq + 3], conv);
            }

            const float r = fast_sigmoid(xrv + conv);
            const float z = fast_sigmoid(xzv + conv);
            const float e2 = __expf(2.f * (xhv + r * conv));
            const float ht = 1.f - 2.f * __builtin_amdgcn_rcpf(e2 + 1.f);
            const int nb = hoffb + (n << 7);             // node byte offset
            const float hp = *(const float*)(hprev + nb);
            const float hn = (1.f - z) * hp + z * ht;

            *(float*)(hnext + nb) = hn;
            __builtin_nontemporal_store(hn, outp + (n << 5));
        }
        if (t != SEQ - 1) {
            if (xmode)
                xcd_barrier(xcnt, xgo, xid, slot, cnt, (unsigned)(t + 1));
            else
                global_barrier(glvl1, groot, (unsigned)(t + 2));
        }
        char* tmp = (char*)hprev; hprev = hnext; hnext = tmp;
        outp += NN * HD;
    }
}

// ---------------- launch ----------------

extern "C" void kernel_launch(void* const* d_in, const int* in_sizes, int n_in,
                              void* d_out, int out_size, void* d_ws, size_t ws_size,
                              hipStream_t stream) {
    const float* x   = (const float*)d_in[0];
    const int*   src = (const int*)d_in[1];
    const int*   dst = (const int*)d_in[2];
    const float* Wr  = (const float*)d_in[3];
    const float* br  = (const float*)d_in[4];
    const float* Wz  = (const float*)d_in[5];
    const float* bz  = (const float*)d_in[6];
    const float* Wh  = (const float*)d_in[7];
    const float* bh  = (const float*)d_in[8];
    const float* Wg  = (const float*)d_in[9];
    const float* bg  = (const float*)d_in[10];
    float* out = (float*)d_out;

    char* ws = (char*)d_ws;
    float* h0 = (float*)ws;            ws += (size_t)BATCH * NN * HD * 4;
    float* h1 = (float*)ws;            ws += (size_t)BATCH * NN * HD * 4;
    float* xr = (float*)ws;            ws += BATCH * HD * 4;
    float* xz = (float*)ws;            ws += BATCH * HD * 4;
    float* xh = (float*)ws;            ws += BATCH * HD * 4;
    int* deg_out = (int*)ws;           ws += NN * 4;
    int* deg_in  = (int*)ws;           ws += NN * 4;
    int* cursor  = (int*)ws;           ws += NN * 4;
    int* row_ptr = (int*)ws;           ws += (NN + 1) * 4;
    int* col_idx = (int*)ws;           ws += NE * 4;
    float* wgt   = (float*)ws;         ws += NE * 4;
    unsigned* glvl1 = (unsigned*)ws;   ws += NGRP * 32 * 4;
    unsigned* groot = (unsigned*)ws;   ws += 32 * 4;
    unsigned* xreg  = (unsigned*)ws;   ws += NXCD * 32 * 4;
    unsigned* xcnt  = (unsigned*)ws;   ws += NXCD * 32 * 4;
    unsigned* xgo   = (unsigned*)ws;   ws += NXCD * 32 * 4;

    hipMemsetAsync(h0, 0, (size_t)BATCH * NN * HD * 4, stream);
    hipMemsetAsync(deg_out, 0, 3 * NN * 4, stream);
    hipMemsetAsync(glvl1, 0, (NGRP * 32 + 32 + 3 * NXCD * 32) * 4, stream);

    count_deg<<<NE / 256, 256, 0, stream>>>(src, dst, deg_out, deg_in);
    scan_rowptr<<<1, 256, 0, stream>>>(deg_in, row_ptr);
    scatter_edges<<<NE / 256, 256, 0, stream>>>(src, dst, deg_out, deg_in, row_ptr,
                                                cursor, col_idx, wgt);
    xgates<<<2, 256, 0, stream>>>(x, Wr, br, Wz, bz, Wh, bh, xr, xz, xh);

    gru_persistent<<<dim3(NBLK), dim3(TPB), 0, stream>>>(
        h0, h1, row_ptr, col_idx, wgt, Wg, bg, xr, xz, xh, out,
        glvl1, groot, xreg, xcnt, xgo);
}

// Round 10
// 740.486 us; speedup vs baseline: 4.0965x; 1.0671x over previous
//
#include <hip/hip_runtime.h>
#include <math.h>

#define BATCH 16
#define IN 128
#define HD 32
#define NN 2048
#define NE 32768
#define SEQ 100
#define TPB 512
#define NBLK 512            // 2 blocks/CU -- PROVEN co-resident (rounds 6-8); do not raise
#define GSZ 32              // global barrier: blocks per group
#define NGRP (NBLK / GSZ)   // 16
#define NXCD 8
#define MAXJ 64             // max (k,wave) node slots per block
#define ECAP 1536           // LDS edge cache entries (int2, 12 KB)

// ---------------- preprocessing ----------------

__global__ void count_deg(const int* __restrict__ src, const int* __restrict__ dst,
                          int* deg_out, int* deg_in) {
    int e = blockIdx.x * blockDim.x + threadIdx.x;
    if (e < NE) {
        atomicAdd(&deg_out[src[e]], 1);
        atomicAdd(&deg_in[dst[e]], 1);
    }
}

__global__ void scan_rowptr(const int* __restrict__ deg_in, int* __restrict__ row_ptr) {
    __shared__ int partial[256];
    int t = threadIdx.x;
    int base = t * 8;
    int vals[8];
    int s = 0;
    for (int j = 0; j < 8; j++) { vals[j] = deg_in[base + j]; s += vals[j]; }
    partial[t] = s;
    __syncthreads();
    if (t == 0) {
        int acc = 0;
        for (int i = 0; i < 256; i++) { int v = partial[i]; partial[i] = acc; acc += v; }
        row_ptr[NN] = acc;
    }
    __syncthreads();
    int acc = partial[t];
    for (int j = 0; j < 8; j++) { row_ptr[base + j] = acc; acc += vals[j]; }
}

// col_idx stores src*HD (element offset of the source node's row)
__global__ void scatter_edges(const int* __restrict__ src, const int* __restrict__ dst,
                              const int* __restrict__ deg_out, const int* __restrict__ deg_in,
                              const int* __restrict__ row_ptr, int* __restrict__ cursor,
                              int* __restrict__ col_idx, float* __restrict__ wgt) {
    int e = blockIdx.x * blockDim.x + threadIdx.x;
    if (e < NE) {
        int s = src[e], d = dst[e];
        int pos = row_ptr[d] + atomicAdd(&cursor[d], 1);
        col_idx[pos] = s * HD;
        float doo = (float)max(deg_out[s], 1);
        float dii = (float)max(deg_in[d], 1);
        wgt[pos] = rsqrtf(doo * dii);
    }
}

__global__ void xgates(const float* __restrict__ x,
                       const float* __restrict__ Wr, const float* __restrict__ br,
                       const float* __restrict__ Wz, const float* __restrict__ bz,
                       const float* __restrict__ Wh, const float* __restrict__ bh,
                       float* __restrict__ xr, float* __restrict__ xz, float* __restrict__ xh) {
    int t = blockIdx.x * blockDim.x + threadIdx.x;
    if (t < BATCH * HD) {
        int b = t / HD, hh = t % HD;
        float ar = br[hh], az = bz[hh], ah = bh[hh];
        const float* xb = x + b * IN;
        for (int i = 0; i < IN; i++) {
            float xv = xb[i];
            ar += xv * Wr[i * HD + hh];
            az += xv * Wz[i * HD + hh];
            ah += xv * Wh[i * HD + hh];
        }
        xr[t] = ar; xz[t] = az; xh[t] = ah;
    }
}

// ---------------- barriers ----------------

// Global two-level barrier with agent fences (proven round 6).
__device__ __forceinline__ void global_barrier(unsigned* __restrict__ lvl1,
                                               unsigned* __restrict__ root,
                                               unsigned step) {
    __syncthreads();
    if (threadIdx.x == 0) {
        const int gid = blockIdx.x / GSZ;
        __builtin_amdgcn_fence(__ATOMIC_RELEASE, "agent");
        __hip_atomic_fetch_add(&lvl1[gid * 32], 1u, __ATOMIC_RELAXED,
                               __HIP_MEMORY_SCOPE_AGENT);
        if ((blockIdx.x % GSZ) == 0) {
            while (__hip_atomic_load(&lvl1[gid * 32], __ATOMIC_RELAXED,
                                     __HIP_MEMORY_SCOPE_AGENT) < GSZ * step)
                __builtin_amdgcn_s_sleep(2);
            __hip_atomic_fetch_add(root, 1u, __ATOMIC_RELAXED,
                                   __HIP_MEMORY_SCOPE_AGENT);
        }
        while (__hip_atomic_load(root, __ATOMIC_RELAXED,
                                 __HIP_MEMORY_SCOPE_AGENT) < NGRP * step)
            __builtin_amdgcn_s_sleep(2);
        __builtin_amdgcn_fence(__ATOMIC_ACQUIRE, "agent");
    }
    __syncthreads();
}

// Per-XCD barrier (proven rounds 7/8). Arrivals spread over 8 cache lines
// (slot&7); leader polls the 8-line sum (monotonic counters -> exact-target
// sum is race-free).
__device__ __forceinline__ void xcd_barrier(unsigned* __restrict__ xcnt,
                                            unsigned* __restrict__ xgo,
                                            int xid, int slot, int cnt, unsigned s) {
    __syncthreads();
    if (threadIdx.x == 0) {
        __hip_atomic_fetch_add(&xcnt[(xid * 8 + (slot & 7)) * 32], 1u,
                               __ATOMIC_RELAXED, __HIP_MEMORY_SCOPE_AGENT);
        if (slot == 0) {
            for (;;) {
                unsigned sum = 0;
#pragma unroll
                for (int i = 0; i < 8; i++)
                    sum += __hip_atomic_load(&xcnt[(xid * 8 + i) * 32],
                                             __ATOMIC_RELAXED, __HIP_MEMORY_SCOPE_AGENT);
                if (sum >= (unsigned)cnt * s) break;
                __builtin_amdgcn_s_sleep(1);
            }
            __hip_atomic_store(&xgo[xid * 32], s, __ATOMIC_RELAXED,
                               __HIP_MEMORY_SCOPE_AGENT);
        } else {
            while (__hip_atomic_load(&xgo[xid * 32], __ATOMIC_RELAXED,
                                     __HIP_MEMORY_SCOPE_AGENT) < s)
                __builtin_amdgcn_s_sleep(1);
        }
    }
    __syncthreads();
    asm volatile("buffer_inv sc0\n\ts_waitcnt vmcnt(0)" ::: "memory");
}

// ---------------- persistent kernel ----------------
// h layout: [B][N][H]. Wave = one node for a batch PAIR:
// lanes 0-31 -> batch b0 (ch 0-31), lanes 32-63 -> batch b0+1.

__device__ __forceinline__ float fast_sigmoid(float x) {
    return __builtin_amdgcn_rcpf(1.f + __expf(-x));
}

__global__ void __launch_bounds__(TPB) gru_persistent(
    float* __restrict__ hA, float* __restrict__ hB,
    const int* __restrict__ row_ptr, const int* __restrict__ col_idx,
    const float* __restrict__ wgt,
    const float* __restrict__ Wg, const float* __restrict__ bg,
    const float* __restrict__ xr, const float* __restrict__ xz,
    const float* __restrict__ xh,
    float* __restrict__ out,
    unsigned* __restrict__ glvl1, unsigned* __restrict__ groot,
    unsigned* __restrict__ xreg, unsigned* __restrict__ xcnt,
    unsigned* __restrict__ xgo)
{
    __shared__ float aggL[TPB];
    __shared__ int jn[MAXJ], jrs[MAXJ], jraw[MAXJ], jplen[MAXJ], jofs[MAXJ];
    __shared__ __align__(16) int2 eLDS[ECAP];   // (byte-offset, bitcast weight)
    __shared__ int shr_slot, shr_cnt, shr_mode, shr_use;

    const int tid = threadIdx.x;
    const int lane = tid & 63;
    const int wid = tid >> 6;        // wave id (0..7)
    const int half = lane >> 5;      // which batch of the pair
    const int l = lane & 31;         // channel

    // physical XCD id [measured: learn_hip m09]
    int xraw;
    asm volatile("s_getreg_b32 %0, hwreg(HW_REG_XCC_ID)" : "=s"(xraw));
    int xid = xraw & 7;

    if (tid == 0)
        shr_slot = (int)__hip_atomic_fetch_add(&xreg[xid * 32], 1u, __ATOMIC_RELAXED,
                                               __HIP_MEMORY_SCOPE_AGENT);
    __syncthreads();
    int slot = shr_slot;

    global_barrier(glvl1, groot, 1u);   // settle registration

    if (tid == 0) {
        int sum = 0, mode = 1, mycnt = 0;
        for (int xx = 0; xx < NXCD; xx++) {
            int c = (int)__hip_atomic_load(&xreg[xx * 32], __ATOMIC_RELAXED,
                                           __HIP_MEMORY_SCOPE_AGENT);
            sum += c;
            if (c < 32) mode = 0;       // guarantees nodes/wave <= 8 (MAXJ)
            if (xx == xid) mycnt = c;
        }
        if (sum != NBLK) mode = 0;
        shr_mode = mode;
        shr_cnt = mycnt;
    }
    __syncthreads();
    const int xmode = shr_mode;
    int cnt = shr_cnt;
    if (!xmode) { xid = blockIdx.x & 7; slot = blockIdx.x >> 3; cnt = NBLK / NXCD; }
    const int wtot = cnt * 8;

    // ---- per-block node metadata (j = k*8 + waveid) ----
    if (tid < MAXJ) {
        int k = tid >> 3, w = tid & 7;
        int n = slot * 8 + w + k * wtot;
        if (n < NN) {
            int rs = row_ptr[n], re = row_ptr[n + 1];
            jn[tid] = n; jrs[tid] = rs; jraw[tid] = re - rs;
            jplen[tid] = (re - rs + 7) & ~7;
        } else {
            jn[tid] = -1; jrs[tid] = 0; jraw[tid] = 0; jplen[tid] = 0;
        }
    }
    __syncthreads();
    if (tid == 0) {
        int o = 0;
        for (int j = 0; j < MAXJ; j++) { jofs[j] = o; o += jplen[j]; }
        shr_use = (o <= ECAP);
    }
    __syncthreads();
    const bool use_lds = (shr_use != 0);

    // ---- stage edges into LDS once (time-invariant), padded to x8 ----
    if (use_lds) {
        for (int k = 0; k < 8; k++) {
            int j = k * 8 + wid;
            if (jn[j] < 0) break;
            int rs = jrs[j], raw = jraw[j], pl = jplen[j], of = jofs[j];
            for (int i = lane; i < pl; i += 64) {
                int2 v;
                if (i < raw) { v.x = col_idx[rs + i] << 2; v.y = __float_as_int(wgt[rs + i]); }
                else         { v.x = 0; v.y = 0; }
                eLDS[of + i] = v;
            }
        }
    }
    __syncthreads();

    // ---- per-thread constants ----
    const int bb = 2 * xid + half;
    const float xrv = xr[bb * HD + l];
    const float xzv = xz[bb * HD + l];
    const float xhv = xh[bb * HD + l];
    const float bgv = bg[l];
    float wgreg[HD];
#pragma unroll
    for (int k = 0; k < HD; k++) wgreg[k] = Wg[k * HD + l];

    const int hoffb = (bb * (NN * HD) + l) * 4;         // byte offset of this thread's lane
    float* outp = out + (size_t)bb * SEQ * (NN * HD) + l;

    const char* hprev = (const char*)hA;
    char* hnext = (char*)hB;

    for (int t = 0; t < SEQ; t++) {
        for (int k = 0; k < 8; k++) {
            const int j = k * 8 + wid;
            const int n = jn[j];
            if (n < 0) break;

            float agg = 0.f;
            if (use_lds) {
                const int4* ep = (const int4*)&eLDS[jofs[j]];   // 2 edges per int4
                const int pl = jplen[j];
                int e = 0;
                // 16 edges per iteration: 16 independent loads in flight
                for (; e + 16 <= pl; e += 16) {
                    int4 p0 = ep[0], p1 = ep[1], p2 = ep[2], p3 = ep[3];
                    int4 p4 = ep[4], p5 = ep[5], p6 = ep[6], p7 = ep[7];
                    ep += 8;
                    float v0 = *(const float*)(hprev + (hoffb + p0.x));
                    float v1 = *(const float*)(hprev + (hoffb + p0.z));
                    float v2 = *(const float*)(hprev + (hoffb + p1.x));
                    float v3 = *(const float*)(hprev + (hoffb + p1.z));
                    float v4 = *(const float*)(hprev + (hoffb + p2.x));
                    float v5 = *(const float*)(hprev + (hoffb + p2.z));
                    float v6 = *(const float*)(hprev + (hoffb + p3.x));
                    float v7 = *(const float*)(hprev + (hoffb + p3.z));
                    float v8 = *(const float*)(hprev + (hoffb + p4.x));
                    float v9 = *(const float*)(hprev + (hoffb + p4.z));
                    float va = *(const float*)(hprev + (hoffb + p5.x));
                    float vb = *(const float*)(hprev + (hoffb + p5.z));
                    float vc = *(const float*)(hprev + (hoffb + p6.x));
                    float vd = *(const float*)(hprev + (hoffb + p6.z));
                    float ve = *(const float*)(hprev + (hoffb + p7.x));
                    float vf = *(const float*)(hprev + (hoffb + p7.z));
                    agg = fmaf(__int_as_float(p0.y), v0, agg);
                    agg = fmaf(__int_as_float(p0.w), v1, agg);
                    agg = fmaf(__int_as_float(p1.y), v2, agg);
                    agg = fmaf(__int_as_float(p1.w), v3, agg);
                    agg = fmaf(__int_as_float(p2.y), v4, agg);
                    agg = fmaf(__int_as_float(p2.w), v5, agg);
                    agg = fmaf(__int_as_float(p3.y), v6, agg);
                    agg = fmaf(__int_as_float(p3.w), v7, agg);
                    agg = fmaf(__int_as_float(p4.y), v8, agg);
                    agg = fmaf(__int_as_float(p4.w), v9, agg);
                    agg = fmaf(__int_as_float(p5.y), va, agg);
                    agg = fmaf(__int_as_float(p5.w), vb, agg);
                    agg = fmaf(__int_as_float(p6.y), vc, agg);
                    agg = fmaf(__int_as_float(p6.w), vd, agg);
                    agg = fmaf(__int_as_float(p7.y), ve, agg);
                    agg = fmaf(__int_as_float(p7.w), vf, agg);
                }
                if (e < pl) {   // pl is a multiple of 8 -> at most one 8-chunk tail
                    int4 p0 = ep[0], p1 = ep[1], p2 = ep[2], p3 = ep[3];
                    float v0 = *(const float*)(hprev + (hoffb + p0.x));
                    float v1 = *(const float*)(hprev + (hoffb + p0.z));
                    float v2 = *(const float*)(hprev + (hoffb + p1.x));
                    float v3 = *(const float*)(hprev + (hoffb + p1.z));
                    float v4 = *(const float*)(hprev + (hoffb + p2.x));
                    float v5 = *(const float*)(hprev + (hoffb + p2.z));
                    float v6 = *(const float*)(hprev + (hoffb + p3.x));
                    float v7 = *(const float*)(hprev + (hoffb + p3.z));
                    agg = fmaf(__int_as_float(p0.y), v0, agg);
                    agg = fmaf(__int_as_float(p0.w), v1, agg);
                    agg = fmaf(__int_as_float(p1.y), v2, agg);
                    agg = fmaf(__int_as_float(p1.w), v3, agg);
                    agg = fmaf(__int_as_float(p2.y), v4, agg);
                    agg = fmaf(__int_as_float(p2.w), v5, agg);
                    agg = fmaf(__int_as_float(p3.y), v6, agg);
                    agg = fmaf(__int_as_float(p3.w), v7, agg);
                }
            } else {   // rare overflow path: stream from global
                const int rs = jrs[j], re = rs + jraw[j];
                for (int e = rs; e < re; e++) {
                    int cb = col_idx[e] << 2;
                    agg = fmaf(wgt[e], *(const float*)(hprev + (hoffb + cb)), agg);
                }
            }

            // matvec: conv[l] = bg[l] + sum_k agg[k] * Wg[k][l]
            // per-wave LDS broadcast (writer wave == reader wave -> lockstep)
            aggL[tid] = agg;
            const float4* arow = (const float4*)&aggL[(tid & ~63) + (half << 5)];
            float conv = bgv;
#pragma unroll
            for (int kq = 0; kq < 8; kq++) {
                float4 a4 = arow[kq];
                conv = fmaf(a4.x, wgreg[4 * kq + 0], conv);
                conv = fmaf(a4.y, wgreg[4 * kq + 1], conv);
                conv = fmaf(a4.z, wgreg[4 * kq + 2], conv);
                conv = fmaf(a4.w, wgreg[4 * kq + 3], conv);
            }

            const float r = fast_sigmoid(xrv + conv);
            const float z = fast_sigmoid(xzv + conv);
            const float e2 = __expf(2.f * (xhv + r * conv));
            const float ht = 1.f - 2.f * __builtin_amdgcn_rcpf(e2 + 1.f);
            const int nb = hoffb + (n << 7);             // node byte offset
            const float hp = *(const float*)(hprev + nb);
            const float hn = fmaf(z, ht - hp, hp);

            *(float*)(hnext + nb) = hn;
            __builtin_nontemporal_store(hn, outp + (n << 5));
        }
        if (t != SEQ - 1) {
            if (xmode)
                xcd_barrier(xcnt, xgo, xid, slot, cnt, (unsigned)(t + 1));
            else
                global_barrier(glvl1, groot, (unsigned)(t + 2));
        }
        char* tmp = (char*)hprev; hprev = hnext; hnext = tmp;
        outp += NN * HD;
    }
}

// ---------------- launch ----------------

extern "C" void kernel_launch(void* const* d_in, const int* in_sizes, int n_in,
                              void* d_out, int out_size, void* d_ws, size_t ws_size,
                              hipStream_t stream) {
    const float* x   = (const float*)d_in[0];
    const int*   src = (const int*)d_in[1];
    const int*   dst = (const int*)d_in[2];
    const float* Wr  = (const float*)d_in[3];
    const float* br  = (const float*)d_in[4];
    const float* Wz  = (const float*)d_in[5];
    const float* bz  = (const float*)d_in[6];
    const float* Wh  = (const float*)d_in[7];
    const float* bh  = (const float*)d_in[8];
    const float* Wg  = (const float*)d_in[9];
    const float* bg  = (const float*)d_in[10];
    float* out = (float*)d_out;

    char* ws = (char*)d_ws;
    float* h0 = (float*)ws;            ws += (size_t)BATCH * NN * HD * 4;
    float* h1 = (float*)ws;            ws += (size_t)BATCH * NN * HD * 4;
    float* xr = (float*)ws;            ws += BATCH * HD * 4;
    float* xz = (float*)ws;            ws += BATCH * HD * 4;
    float* xh = (float*)ws;            ws += BATCH * HD * 4;
    int* deg_out = (int*)ws;           ws += NN * 4;
    int* deg_in  = (int*)ws;           ws += NN * 4;
    int* cursor  = (int*)ws;           ws += NN * 4;
    int* row_ptr = (int*)ws;           ws += (NN + 1) * 4;
    int* col_idx = (int*)ws;           ws += NE * 4;
    float* wgt   = (float*)ws;         ws += NE * 4;
    unsigned* glvl1 = (unsigned*)ws;   ws += NGRP * 32 * 4;
    unsigned* groot = (unsigned*)ws;   ws += 32 * 4;
    unsigned* xreg  = (unsigned*)ws;   ws += NXCD * 32 * 4;
    unsigned* xcnt  = (unsigned*)ws;   ws += NXCD * 8 * 32 * 4;
    unsigned* xgo   = (unsigned*)ws;   ws += NXCD * 32 * 4;

    hipMemsetAsync(h0, 0, (size_t)BATCH * NN * HD * 4, stream);
    hipMemsetAsync(deg_out, 0, 3 * NN * 4, stream);
    hipMemsetAsync(glvl1, 0,
                   (NGRP * 32 + 32 + NXCD * 32 + NXCD * 8 * 32 + NXCD * 32) * 4, stream);

    count_deg<<<NE / 256, 256, 0, stream>>>(src, dst, deg_out, deg_in);
    scan_rowptr<<<1, 256, 0, stream>>>(deg_in, row_ptr);
    scatter_edges<<<NE / 256, 256, 0, stream>>>(src, dst, deg_out, deg_in, row_ptr,
                                                cursor, col_idx, wgt);
    xgates<<<2, 256, 0, stream>>>(x, Wr, br, Wz, bz, Wh, bh, xr, xz, xh);

    gru_persistent<<<dim3(NBLK), dim3(TPB), 0, stream>>>(
        h0, h1, row_ptr, col_idx, wgt, Wg, bg, xr, xz, xh, out,
        glvl1, groot, xreg, xcnt, xgo);
}